// Round 18
// baseline (313.752 us; speedup 1.0000x reference)
//
#include <hip/hip_runtime.h>

#define DD 64
#define WIN 128    // CSR slots per block
#define MSTR 132   // ldsMT row stride (bf16): 264B rows, 8B-aligned

typedef __attribute__((ext_vector_type(8))) short bf16x8;
typedef __attribute__((ext_vector_type(4))) float f32x4;

__device__ __forceinline__ float fast_tanh(float x) {
    float e = __builtin_amdgcn_exp2f(x * 2.885390081777927f); // 2x * log2(e)
    return 1.0f - 2.0f * __builtin_amdgcn_rcpf(e + 1.0f);
}

__device__ __forceinline__ unsigned f2bf(float f) {
    union { float f; unsigned u; } v; v.f = f;
    return (v.u + 0x7FFFu + ((v.u >> 16) & 1u)) >> 16;   // RNE
}

__device__ __forceinline__ float bf2f(unsigned short u) {
    union { unsigned u; float f; } v; v.u = ((unsigned)u) << 16;
    return v.f;
}

__device__ __forceinline__ bf16x8 cvt8(float4 f0, float4 f1) {
    union { unsigned u[4]; bf16x8 v; } r;
    r.u[0] = f2bf(f0.x) | (f2bf(f0.y) << 16);
    r.u[1] = f2bf(f0.z) | (f2bf(f0.w) << 16);
    r.u[2] = f2bf(f1.x) | (f2bf(f1.y) << 16);
    r.u[3] = f2bf(f1.z) | (f2bf(f1.w) << 16);
    return r.v;
}

// ext-vector variant (native vector type: valid for nontemporal builtins)
__device__ __forceinline__ bf16x8 cvt8v(f32x4 f0, f32x4 f1) {
    union { unsigned u[4]; bf16x8 v; } r;
    r.u[0] = f2bf(f0[0]) | (f2bf(f0[1]) << 16);
    r.u[1] = f2bf(f0[2]) | (f2bf(f0[3]) << 16);
    r.u[2] = f2bf(f1[0]) | (f2bf(f1[1]) << 16);
    r.u[3] = f2bf(f1[2]) | (f2bf(f1[3]) << 16);
    return r.v;
}

// ---------------- CSR build ----------------

// replaces hipMemsetAsync(deg): the runtime's graph-captured fillBuffer of
// 200KB ran at 116us/replay (round-17 PMC) -- a plain kernel is ~2us.
__global__ void __launch_bounds__(256) zero_deg(int* __restrict__ deg, int N)
{
    int i = blockIdx.x * 256 + threadIdx.x;
    if (i < N) deg[i] = 0;
}

__global__ void __launch_bounds__(256) count_deg(
    const int* __restrict__ dst, int* __restrict__ deg, int E)
{
    int e = blockIdx.x * 256 + threadIdx.x;
    if (e < E) atomicAdd(&deg[dst[e]], 1);
}

// parallel scan, 3 kernels: per-256-chunk partials -> base scan -> expand
__global__ void __launch_bounds__(256) scan_partial(
    const int* __restrict__ deg, int* __restrict__ part, int N)
{
    __shared__ int red[256];
    int b = blockIdx.x, t = threadIdx.x;
    int i = b * 256 + t;
    red[t] = (i < N) ? deg[i] : 0;
    __syncthreads();
    #pragma unroll
    for (int d = 128; d > 0; d >>= 1) {
        if (t < d) red[t] += red[t + d];
        __syncthreads();
    }
    if (t == 0) part[b] = red[0];
}

__global__ void __launch_bounds__(1024) scan_base(int* __restrict__ part, int nb)
{
    __shared__ int sc[1024];
    int t = threadIdx.x;
    sc[t] = (t < nb) ? part[t] : 0;
    __syncthreads();
    for (int d = 1; d < 1024; d <<= 1) {
        int v = 0;
        if (t >= d) v = sc[t - d];
        __syncthreads();
        if (t >= d) sc[t] += v;
        __syncthreads();
    }
    if (t < nb) part[t] = (t == 0) ? 0 : sc[t - 1];
}

__global__ void __launch_bounds__(256) scan_expand(
    const int* __restrict__ deg, const int* __restrict__ part,
    int* __restrict__ off, int* __restrict__ cursor, int N)
{
    __shared__ int sc[256];
    int b = blockIdx.x, t = threadIdx.x;
    int i = b * 256 + t;
    int d = (i < N) ? deg[i] : 0;
    sc[t] = d;
    __syncthreads();
    for (int s = 1; s < 256; s <<= 1) {
        int v = 0;
        if (t >= s) v = sc[t - s];
        __syncthreads();
        if (t >= s) sc[t] += v;
        __syncthreads();
    }
    int excl = sc[t] - d;
    if (i < N) {
        int o = part[b] + excl;
        off[i] = o; cursor[i] = o;
        if (i == N - 1) off[N] = o + d;
    }
}

// fallback single-block scan (used only if N/256 > 1024)
__global__ void __launch_bounds__(1024) scan_kernel(
    const int* __restrict__ deg, int* __restrict__ off,
    int* __restrict__ cursor, int N)
{
    __shared__ int part[1024];
    int t = threadIdx.x;
    int per = (N + 1023) / 1024;
    int lo = t * per;
    int hi = lo + per; if (hi > N) hi = N;
    int s = 0;
    for (int i = lo; i < hi; ++i) s += deg[i];
    part[t] = s;
    __syncthreads();
    for (int d = 1; d < 1024; d <<= 1) {
        int v = 0;
        if (t >= d) v = part[t - d];
        __syncthreads();
        if (t >= d) part[t] += v;
        __syncthreads();
    }
    int run = (t == 0) ? 0 : part[t - 1];
    for (int i = lo; i < hi; ++i) {
        off[i] = run; cursor[i] = run;
        run += deg[i];
    }
    if (lo < N && hi == N) off[N] = run;
}

// also writes srcc[slot] = src[e] (src[e] coalesced here since e = tid)
__global__ void __launch_bounds__(256) fill_eidx(
    const int* __restrict__ dst, const int* __restrict__ src,
    int* __restrict__ cursor, int* __restrict__ eidx,
    int* __restrict__ srcc, int E)
{
    int e = blockIdx.x * 256 + threadIdx.x;
    if (e < E) {
        int slot = atomicAdd(&cursor[dst[e]], 1);
        eidx[slot] = e;
        srcc[slot] = src[e];
    }
}

// wt[m][n*64+k] = bf16(W_m[(koff+k)*64 + n]) for the 8 half-matrices:
// 0:Wm1 top  1:Wm1 bot  2:Wu1 top  3:Wu1 bot  4:Wm2 top  5:Wm2 bot  6:Wu2 top  7:Wu2 bot
__global__ void __launch_bounds__(256) prep_wt_all(
    const float* __restrict__ Wm1, const float* __restrict__ Wu1,
    const float* __restrict__ Wm2, const float* __restrict__ Wu2,
    unsigned short* __restrict__ wt)
{
    int i = blockIdx.x * 256 + threadIdx.x;
    if (i >= 8 * 4096) return;
    int m = i >> 12;
    int j = i & 4095;
    int n = j >> 6, k = j & 63;
    const float* W; int koff;
    switch (m) {
        case 0: W = Wm1; koff = 0;  break;
        case 1: W = Wm1; koff = 64; break;
        case 2: W = Wu1; koff = 0;  break;
        case 3: W = Wu1; koff = 64; break;
        case 4: W = Wm2; koff = 0;  break;
        case 5: W = Wm2; koff = 64; break;
        case 6: W = Wu2; koff = 0;  break;
        default: W = Wu2; koff = 64; break;
    }
    wt[i] = (unsigned short)f2bf(W[(koff + k) * 64 + n]);
}

// ---------------- MFMA node GEMM ----------------
// out[r] = op(A1[r]@W1 (+ A2[r]@W2) + bias)
// OUTK: fuse final readout, out1[r] = tanh(row)·Wo + bo via shfl reduce.
// NEXT: after computing h = tanh(...), also compute hm = h@Wn + biasn
//       (h goes C-layout -> swizzled LDS -> A-fragments) and zero pooled.
template<bool TWO, bool TANH, bool ZEROP, bool OUTK, bool NEXT>
__global__ void __launch_bounds__(256, 4) node_mfma(
    const float* __restrict__ A1, const float* __restrict__ A2,
    const unsigned short* __restrict__ wt1, const unsigned short* __restrict__ wt2,
    const float* __restrict__ bias, float* __restrict__ outp,
    float* __restrict__ pooled,
    const float* __restrict__ Wo, const float* __restrict__ bo,
    float* __restrict__ outv,
    const unsigned short* __restrict__ wtn, const float* __restrict__ biasn,
    float* __restrict__ hmout, int N)
{
    __shared__ unsigned short ldsH[NEXT ? 128 * 64 : 8];

    const int t = threadIdx.x;
    const int row0 = blockIdx.x * 128;
    const int wv = t >> 6, l = t & 63;
    const int lrow = l & 15, lk = l >> 4;

    f32x4 acc[2][4];
    {
        bf16x8 bfr[4][2];
        #pragma unroll
        for (int cg = 0; cg < 4; ++cg)
            #pragma unroll
            for (int k2 = 0; k2 < 2; ++k2)
                bfr[cg][k2] = *reinterpret_cast<const bf16x8*>(
                    wt1 + (cg * 16 + lrow) * 64 + (lk + k2 * 4) * 8);
        #pragma unroll
        for (int er = 0; er < 2; ++er) {
            int r = row0 + wv * 32 + er * 16 + lrow;
            bf16x8 a0, a1;
            if (r < N) {
                const float4* ap = reinterpret_cast<const float4*>(A1 + (size_t)r * 64);
                a0 = cvt8(ap[lk * 2],       ap[lk * 2 + 1]);
                a1 = cvt8(ap[(lk + 4) * 2], ap[(lk + 4) * 2 + 1]);
            } else {
                a0 = bf16x8{0,0,0,0,0,0,0,0}; a1 = a0;
            }
            #pragma unroll
            for (int cg = 0; cg < 4; ++cg) {
                f32x4 zz = {0.f, 0.f, 0.f, 0.f};
                acc[er][cg] = __builtin_amdgcn_mfma_f32_16x16x32_bf16(a0, bfr[cg][0], zz, 0, 0, 0);
                acc[er][cg] = __builtin_amdgcn_mfma_f32_16x16x32_bf16(a1, bfr[cg][1], acc[er][cg], 0, 0, 0);
            }
        }
    }
    if (TWO) {
        bf16x8 bfr[4][2];
        #pragma unroll
        for (int cg = 0; cg < 4; ++cg)
            #pragma unroll
            for (int k2 = 0; k2 < 2; ++k2)
                bfr[cg][k2] = *reinterpret_cast<const bf16x8*>(
                    wt2 + (cg * 16 + lrow) * 64 + (lk + k2 * 4) * 8);
        #pragma unroll
        for (int er = 0; er < 2; ++er) {
            int r = row0 + wv * 32 + er * 16 + lrow;
            bf16x8 a0, a1;
            if (r < N) {
                const float4* ap = reinterpret_cast<const float4*>(A2 + (size_t)r * 64);
                a0 = cvt8(ap[lk * 2],       ap[lk * 2 + 1]);
                a1 = cvt8(ap[(lk + 4) * 2], ap[(lk + 4) * 2 + 1]);
            } else {
                a0 = bf16x8{0,0,0,0,0,0,0,0}; a1 = a0;
            }
            #pragma unroll
            for (int cg = 0; cg < 4; ++cg) {
                acc[er][cg] = __builtin_amdgcn_mfma_f32_16x16x32_bf16(a0, bfr[cg][0], acc[er][cg], 0, 0, 0);
                acc[er][cg] = __builtin_amdgcn_mfma_f32_16x16x32_bf16(a1, bfr[cg][1], acc[er][cg], 0, 0, 0);
            }
        }
    }

    if (!OUTK) {
        // epilogue: C/D mapping col=lane&15, row=(lane>>4)*4+reg (verified)
        #pragma unroll
        for (int er = 0; er < 2; ++er) {
            int rbl = wv * 32 + er * 16 + (lk << 2);   // local row base
            #pragma unroll
            for (int cg = 0; cg < 4; ++cg) {
                int col = cg * 16 + lrow;
                float bv = bias[col];
                #pragma unroll
                for (int j = 0; j < 4; ++j) {
                    int r = row0 + rbl + j;
                    float v = acc[er][cg][j] + bv;
                    if (TANH) v = fast_tanh(v);
                    if (r < N) {
                        outp[(size_t)r * 64 + col] = v;
                        if (ZEROP) pooled[(size_t)r * 64 + col] = 0.f;
                    }
                    if (NEXT) {
                        int lr = rbl + j;
                        ldsH[(lr * 8 + ((col >> 3) ^ (lr & 7))) * 8 + (col & 7)] =
                            (unsigned short)f2bf(v);
                    }
                }
            }
        }
    } else {
        // fused readout: out[r] = tanh(row+bias)·Wo + bo
        float p0[2], p1[2], p2[2], p3[2];
        #pragma unroll
        for (int er = 0; er < 2; ++er) { p0[er]=0.f; p1[er]=0.f; p2[er]=0.f; p3[er]=0.f; }
        #pragma unroll
        for (int er = 0; er < 2; ++er) {
            #pragma unroll
            for (int cg = 0; cg < 4; ++cg) {
                int col = cg * 16 + lrow;
                float bv = bias[col];
                float wo = Wo[col];
                p0[er] += fast_tanh(acc[er][cg][0] + bv) * wo;
                p1[er] += fast_tanh(acc[er][cg][1] + bv) * wo;
                p2[er] += fast_tanh(acc[er][cg][2] + bv) * wo;
                p3[er] += fast_tanh(acc[er][cg][3] + bv) * wo;
            }
        }
        #pragma unroll
        for (int m = 1; m < 16; m <<= 1) {
            #pragma unroll
            for (int er = 0; er < 2; ++er) {
                p0[er] += __shfl_xor(p0[er], m, 64);
                p1[er] += __shfl_xor(p1[er], m, 64);
                p2[er] += __shfl_xor(p2[er], m, 64);
                p3[er] += __shfl_xor(p3[er], m, 64);
            }
        }
        if (lrow < 4) {
            float bov = bo[0];
            #pragma unroll
            for (int er = 0; er < 2; ++er) {
                int r = row0 + wv * 32 + er * 16 + (lk << 2) + lrow;
                float pv = (lrow == 0) ? p0[er] : (lrow == 1) ? p1[er]
                         : (lrow == 2) ? p2[er] : p3[er];
                if (r < N) outv[r] = pv + bov;
            }
        }
    }

    if (NEXT) {
        __syncthreads();
        // second GEMM: hm = h @ Wn + biasn (h from swizzled LDS)
        bf16x8 bfrn[4][2];
        #pragma unroll
        for (int cg = 0; cg < 4; ++cg)
            #pragma unroll
            for (int k2 = 0; k2 < 2; ++k2)
                bfrn[cg][k2] = *reinterpret_cast<const bf16x8*>(
                    wtn + (cg * 16 + lrow) * 64 + (lk + k2 * 4) * 8);
        f32x4 accn[2][4];
        #pragma unroll
        for (int er = 0; er < 2; ++er) {
            int row = wv * 32 + er * 16 + lrow;
            bf16x8 a0 = *reinterpret_cast<const bf16x8*>(
                &ldsH[(row * 8 + ((lk + 0) ^ (row & 7))) * 8]);
            bf16x8 a1 = *reinterpret_cast<const bf16x8*>(
                &ldsH[(row * 8 + ((lk + 4) ^ (row & 7))) * 8]);
            #pragma unroll
            for (int cg = 0; cg < 4; ++cg) {
                f32x4 zz = {0.f, 0.f, 0.f, 0.f};
                accn[er][cg] = __builtin_amdgcn_mfma_f32_16x16x32_bf16(a0, bfrn[cg][0], zz, 0, 0, 0);
                accn[er][cg] = __builtin_amdgcn_mfma_f32_16x16x32_bf16(a1, bfrn[cg][1], accn[er][cg], 0, 0, 0);
            }
        }
        #pragma unroll
        for (int er = 0; er < 2; ++er) {
            int rbl = wv * 32 + er * 16 + (lk << 2);
            #pragma unroll
            for (int cg = 0; cg < 4; ++cg) {
                int col = cg * 16 + lrow;
                float bv = biasn[col];
                #pragma unroll
                for (int j = 0; j < 4; ++j) {
                    int r = row0 + rbl + j;
                    if (r < N) {
                        hmout[(size_t)r * 64 + col] = accn[er][cg][j] + bv;
                        pooled[(size_t)r * 64 + col] = 0.f;
                    }
                }
            }
        }
    }
}

// ---------------- MFMA fused edge kernel v9 (round-17, unchanged) ----------------
__global__ void __launch_bounds__(256, 4) fused_edge_gather(
    const float* __restrict__ ef, unsigned short* __restrict__ efb,
    const float* __restrict__ hm,
    const int* __restrict__ srcc, const int* __restrict__ dst,
    const int* __restrict__ off, const int* __restrict__ eidx,
    const unsigned short* __restrict__ wtb, float* __restrict__ pooled,
    int E, int N, int layer1)
{
    __shared__ unsigned short ldsMT[64 * MSTR];   // [channel][slot] (16.9 KB)
    __shared__ int ldsE[WIN];
    __shared__ int ldsSrc[WIN];

    const int t  = threadIdx.x;
    const int s0 = blockIdx.x * WIN;
    const int wv = t >> 6, l = t & 63;
    const int lrow = l & 15, lk = l >> 4;

    // stage edge ids + src rows for the window (both coalesced)
    if (t < WIN) {
        int slot = s0 + t;
        ldsE[t]   = (slot < E) ? eidx[slot] : 0;
        ldsSrc[t] = (slot < E) ? srcc[slot] : 0;
    }

    // B fragments from global (8 KB, L2-hot broadcast)
    bf16x8 bfr[4][2];
    #pragma unroll
    for (int cg = 0; cg < 4; ++cg)
        #pragma unroll
        for (int k2 = 0; k2 < 2; ++k2)
            bfr[cg][k2] = *reinterpret_cast<const bf16x8*>(
                wtb + (cg * 16 + lrow) * 64 + (lk + k2 * 4) * 8);

    __syncthreads();

    {
        // A fragments direct from global (+ efb persist on layer 1).
        // All read-once streams are NONTEMPORAL (don't evict hm from L3).
        bf16x8 afr[2][2];
        #pragma unroll
        for (int er = 0; er < 2; ++er) {
            int row = wv * 32 + er * 16 + lrow;
            int slotr = s0 + row;
            if (slotr < E) {
                if (layer1) {
                    int e = ldsE[row];
                    const f32x4* ap = reinterpret_cast<const f32x4*>(ef + (size_t)e * 64);
                    #pragma unroll
                    for (int k2 = 0; k2 < 2; ++k2) {
                        int cc = lk + k2 * 4;
                        f32x4 f0 = __builtin_nontemporal_load(ap + cc * 2);
                        f32x4 f1 = __builtin_nontemporal_load(ap + cc * 2 + 1);
                        bf16x8 v = cvt8v(f0, f1);
                        afr[er][k2] = v;
                        __builtin_nontemporal_store(
                            v, reinterpret_cast<bf16x8*>(efb + (size_t)slotr * 64 + cc * 8));
                    }
                } else {
                    #pragma unroll
                    for (int k2 = 0; k2 < 2; ++k2) {
                        int cc = lk + k2 * 4;
                        afr[er][k2] = __builtin_nontemporal_load(
                            reinterpret_cast<const bf16x8*>(efb + (size_t)slotr * 64 + cc * 8));
                    }
                }
            } else {
                bf16x8 z = {0,0,0,0,0,0,0,0};
                afr[er][0] = z; afr[er][1] = z;
            }
        }

        // MFMA [128x64] = A @ Wt; epilogue: + hm[src] (parallel 16-lane x 64B
        // contiguous gathers, CACHED - hm is the hot set), tanh, bf16 -> ldsMT
        #pragma unroll
        for (int er = 0; er < 2; ++er) {
            f32x4 acc[4];
            #pragma unroll
            for (int cg = 0; cg < 4; ++cg) {
                f32x4 zz = {0.f, 0.f, 0.f, 0.f};
                acc[cg] = __builtin_amdgcn_mfma_f32_16x16x32_bf16(
                    afr[er][0], bfr[cg][0], zz, 0, 0, 0);
                acc[cg] = __builtin_amdgcn_mfma_f32_16x16x32_bf16(
                    afr[er][1], bfr[cg][1], acc[cg], 0, 0, 0);
            }
            int rb = wv * 32 + er * 16 + (lk << 2);
            int sA = ldsSrc[rb + 0], sB = ldsSrc[rb + 1];
            int sC = ldsSrc[rb + 2], sD = ldsSrc[rb + 3];
            #pragma unroll
            for (int cg = 0; cg < 4; ++cg) {
                int col = cg * 16 + lrow;
                float hA = hm[(size_t)sA * 64 + col];
                float hB = hm[(size_t)sB * 64 + col];
                float hC = hm[(size_t)sC * 64 + col];
                float hD = hm[(size_t)sD * 64 + col];
                unsigned short* mcol = &ldsMT[col * MSTR];
                ushort4 m4;
                m4.x = (unsigned short)f2bf(fast_tanh(acc[cg][0] + hA));
                m4.y = (unsigned short)f2bf(fast_tanh(acc[cg][1] + hB));
                m4.z = (unsigned short)f2bf(fast_tanh(acc[cg][2] + hC));
                m4.w = (unsigned short)f2bf(fast_tanh(acc[cg][3] + hD));
                *reinterpret_cast<ushort4*>(&mcol[rb]) = m4;
            }
        }
    }
    __syncthreads();

    // phase 2: segment-sum over the window; wave per node, lane = channel;
    // lane l reads consecutive slots of its channel row -> ushort4 loads.
    {
        int ce = s0 + WIN; if (ce > E) ce = E;
        if (s0 < E) {
            int df = dst[ldsE[0]];
            int dl = dst[ldsE[ce - 1 - s0]];
            const unsigned short* mrow = &ldsMT[l * MSTR];
            for (int n = df + wv; n <= dl; n += 4) {
                int lo = off[n], hi = off[n + 1];
                int clo = lo > s0 ? lo : s0;
                int chi = hi < ce ? hi : ce;
                if (clo >= chi) continue;
                float v = 0.f;
                int q = clo - s0, qe = chi - s0;
                for (; (q & 3) && q < qe; ++q) v += bf2f(mrow[q]);
                for (; q + 3 < qe; q += 4) {
                    ushort4 m4 = *reinterpret_cast<const ushort4*>(mrow + q);
                    v += (bf2f(m4.x) + bf2f(m4.y)) + (bf2f(m4.z) + bf2f(m4.w));
                }
                for (; q < qe; ++q) v += bf2f(mrow[q]);
                if (lo >= s0 && hi <= ce) pooled[(size_t)n * 64 + l] = v;
                else atomicAdd(pooled + (size_t)n * 64 + l, v);
            }
        }
    }
}

// ---------------- scalar fallback kernels (ws too small; fp32 exact) ----------------

__global__ void __launch_bounds__(256, 2) node_transform(
    const float* __restrict__ h, const float* __restrict__ W,
    const float* __restrict__ b, float* __restrict__ hm,
    float* __restrict__ pooled, int N)
{
    int n = blockIdx.x * 256 + threadIdx.x;
    if (n >= N) return;
    float acc[DD];
    #pragma unroll
    for (int j = 0; j < DD; ++j) acc[j] = b[j];
    const float4* hrow = reinterpret_cast<const float4*>(h + (size_t)n * DD);
    #pragma unroll
    for (int kk = 0; kk < DD / 4; ++kk) {
        float4 a = hrow[kk];
        const float* Wr = W + kk * 4 * DD;
        #pragma unroll
        for (int j = 0; j < DD; ++j)
            acc[j] += a.x * Wr[j] + a.y * Wr[DD + j]
                    + a.z * Wr[2 * DD + j] + a.w * Wr[3 * DD + j];
    }
    float4* orow = reinterpret_cast<float4*>(hm + (size_t)n * DD);
    float4* prow = reinterpret_cast<float4*>(pooled + (size_t)n * DD);
    #pragma unroll
    for (int jj = 0; jj < DD / 4; ++jj) {
        orow[jj] = make_float4(acc[4*jj], acc[4*jj+1], acc[4*jj+2], acc[4*jj+3]);
        prow[jj] = make_float4(0.f, 0.f, 0.f, 0.f);
    }
}

__global__ void __launch_bounds__(256, 2) edge_kernel_atomic(
    const float* __restrict__ ef, const float* __restrict__ hm,
    const int* __restrict__ src, const int* __restrict__ dst,
    const float* __restrict__ W, float* __restrict__ pooled, int E)
{
    int e = blockIdx.x * 256 + threadIdx.x;
    if (e >= E) return;
    int s = src[e];
    int d = dst[e];
    float acc[DD];
    #pragma unroll
    for (int j = 0; j < DD; ++j) acc[j] = 0.0f;
    const float4* erow = reinterpret_cast<const float4*>(ef + (size_t)e * DD);
    #pragma unroll
    for (int kk = 0; kk < DD / 4; ++kk) {
        float4 a = erow[kk];
        const float* Wr = W + kk * 4 * DD;
        #pragma unroll
        for (int j = 0; j < DD; ++j)
            acc[j] += a.x * Wr[j] + a.y * Wr[DD + j]
                    + a.z * Wr[2 * DD + j] + a.w * Wr[3 * DD + j];
    }
    const float4* hrow = reinterpret_cast<const float4*>(hm + (size_t)s * DD);
    float* prow = pooled + (size_t)d * DD;
    #pragma unroll
    for (int jj = 0; jj < DD / 4; ++jj) {
        float4 hv = hrow[jj];
        atomicAdd(prow + 4*jj + 0, fast_tanh(acc[4*jj+0] + hv.x));
        atomicAdd(prow + 4*jj + 1, fast_tanh(acc[4*jj+1] + hv.y));
        atomicAdd(prow + 4*jj + 2, fast_tanh(acc[4*jj+2] + hv.z));
        atomicAdd(prow + 4*jj + 3, fast_tanh(acc[4*jj+3] + hv.w));
    }
}

__global__ void __launch_bounds__(256, 2) update_kernel(
    const float* __restrict__ h, const float* __restrict__ pooled,
    const float* __restrict__ Wu, const float* __restrict__ bu,
    float* __restrict__ hout, int N)
{
    int n = blockIdx.x * 256 + threadIdx.x;
    if (n >= N) return;
    float acc[DD];
    #pragma unroll
    for (int j = 0; j < DD; ++j) acc[j] = bu[j];
    const float4* hrow = reinterpret_cast<const float4*>(h + (size_t)n * DD);
    #pragma unroll
    for (int kk = 0; kk < DD / 4; ++kk) {
        float4 a = hrow[kk];
        const float* Wr = Wu + kk * 4 * DD;
        #pragma unroll
        for (int j = 0; j < DD; ++j)
            acc[j] += a.x * Wr[j] + a.y * Wr[DD + j]
                    + a.z * Wr[2 * DD + j] + a.w * Wr[3 * DD + j];
    }
    const float4* prow = reinterpret_cast<const float4*>(pooled + (size_t)n * DD);
    #pragma unroll
    for (int kk = 0; kk < DD / 4; ++kk) {
        float4 a = prow[kk];
        const float* Wr = Wu + (DD + kk * 4) * DD;
        #pragma unroll
        for (int j = 0; j < DD; ++j)
            acc[j] += a.x * Wr[j] + a.y * Wr[DD + j]
                    + a.z * Wr[2 * DD + j] + a.w * Wr[3 * DD + j];
    }
    float4* orow = reinterpret_cast<float4*>(hout + (size_t)n * DD);
    #pragma unroll
    for (int jj = 0; jj < DD / 4; ++jj)
        orow[jj] = make_float4(fast_tanh(acc[4*jj]),   fast_tanh(acc[4*jj+1]),
                               fast_tanh(acc[4*jj+2]), fast_tanh(acc[4*jj+3]));
}

__global__ void __launch_bounds__(256) out_kernel(
    const float* __restrict__ h, const float* __restrict__ Wo,
    const float* __restrict__ bo, float* __restrict__ out, int N)
{
    int n = blockIdx.x * 256 + threadIdx.x;
    if (n >= N) return;
    const float4* hrow = reinterpret_cast<const float4*>(h + (size_t)n * DD);
    float acc = bo[0];
    #pragma unroll
    for (int kk = 0; kk < DD / 4; ++kk) {
        float4 a = hrow[kk];
        acc += a.x * Wo[4*kk] + a.y * Wo[4*kk+1] + a.z * Wo[4*kk+2] + a.w * Wo[4*kk+3];
    }
    out[n] = acc;
}

extern "C" void kernel_launch(void* const* d_in, const int* in_sizes, int n_in,
                              void* d_out, int out_size, void* d_ws, size_t ws_size,
                              hipStream_t stream) {
    const float* node = (const float*)d_in[0];
    const float* ef   = (const float*)d_in[1];
    const int*   src  = (const int*)d_in[2];
    const int*   dst  = (const int*)d_in[3];
    const float* Wm1  = (const float*)d_in[4];
    const float* bm1  = (const float*)d_in[5];
    const float* Wu1  = (const float*)d_in[6];
    const float* bu1  = (const float*)d_in[7];
    const float* Wm2  = (const float*)d_in[8];
    const float* bm2  = (const float*)d_in[9];
    const float* Wu2  = (const float*)d_in[10];
    const float* bu2  = (const float*)d_in[11];
    const float* Wo   = (const float*)d_in[12];
    const float* bo   = (const float*)d_in[13];
    float* out = (float*)d_out;

    const int N = in_sizes[0] / DD;
    const int E = in_sizes[2];

    // ws layout
    char* p = (char*)d_ws;
    float* h1     = (float*)p; p += (size_t)N * DD * 4;
    float* h2     = (float*)p; p += (size_t)N * DD * 4;   // fallback only
    float* hm     = (float*)p; p += (size_t)N * DD * 4;
    float* pooled = (float*)p; p += (size_t)N * DD * 4;
    unsigned short* efb = (unsigned short*)p; p += (size_t)E * DD * 2;
    unsigned short* wt  = (unsigned short*)p; p += (size_t)8 * DD * DD * 2;
    int*   deg    = (int*)p;   p += (size_t)N * 4;
    int*   off    = (int*)p;   p += (size_t)(N + 1) * 4;
    int*   cursor = (int*)p;   p += (size_t)N * 4;
    int*   eidx   = (int*)p;   p += (size_t)E * 4;
    int*   srcc   = (int*)p;   p += (size_t)E * 4;
    int*   part   = (int*)p;   p += (size_t)1024 * 4;
    size_t needed = (size_t)(p - (char*)d_ws);

    dim3 blk(256);
    int nbN = (N + 255) / 256;
    int nbE = (E + 255) / 256;
    int nbE2 = (E + WIN - 1) / WIN;
    int nbT = (N + 127) / 128;
    int nbS = (N + 255) / 256;   // scan chunks of 256

    if (ws_size >= needed) {
        // ---- CSR build + weight prep (stateless: rebuilt every call) ----
        zero_deg<<<nbS, blk, 0, stream>>>(deg, N);   // NOT hipMemsetAsync (116us fill!)
        count_deg<<<nbE, blk, 0, stream>>>(dst, deg, E);
        if (nbS <= 1024) {
            scan_partial<<<nbS, blk, 0, stream>>>(deg, part, N);
            scan_base<<<1, 1024, 0, stream>>>(part, nbS);
            scan_expand<<<nbS, blk, 0, stream>>>(deg, part, off, cursor, N);
        } else {
            scan_kernel<<<1, 1024, 0, stream>>>(deg, off, cursor, N);
        }
        fill_eidx<<<nbE, blk, 0, stream>>>(dst, src, cursor, eidx, srcc, E);
        prep_wt_all<<<128, blk, 0, stream>>>(Wm1, Wu1, Wm2, Wu2, wt);

        // ---- layer 1 ----
        node_mfma<false, false, true, false, false><<<nbT, blk, 0, stream>>>(
            node, nullptr, wt + 0 * 4096, nullptr, bm1, hm, pooled,
            nullptr, nullptr, nullptr, nullptr, nullptr, nullptr, N);
        fused_edge_gather<<<nbE2, blk, 0, stream>>>(ef, efb, hm, srcc, dst, off, eidx,
                                                    wt + 1 * 4096, pooled, E, N, 1);
        // update1 fused with node_transform2: h1 + hm2 in one pass, zero pooled
        node_mfma<true, true, false, false, true><<<nbT, blk, 0, stream>>>(
            node, pooled, wt + 2 * 4096, wt + 3 * 4096, bu1, h1, pooled,
            nullptr, nullptr, nullptr, wt + 4 * 4096, bm2, hm, N);

        // ---- layer 2 ----
        fused_edge_gather<<<nbE2, blk, 0, stream>>>(ef, efb, hm, srcc, dst, off, eidx,
                                                    wt + 5 * 4096, pooled, E, N, 0);
        // update2 fused with readout: h2 never materialized
        node_mfma<true, true, false, true, false><<<nbT, blk, 0, stream>>>(
            h1, pooled, wt + 6 * 4096, wt + 7 * 4096, bu2, nullptr, nullptr,
            Wo, bo, out, nullptr, nullptr, nullptr, N);
    } else {
        // ---- fallback: atomic scatter path (fp32 exact) ----
        node_transform<<<nbN, blk, 0, stream>>>(node, Wm1, bm1, hm, pooled, N);
        edge_kernel_atomic<<<nbE, blk, 0, stream>>>(ef, hm, src, dst, Wm1 + DD * DD, pooled, E);
        update_kernel<<<nbN, blk, 0, stream>>>(node, pooled, Wu1, bu1, h1, N);

        node_transform<<<nbN, blk, 0, stream>>>(h1, Wm2, bm2, hm, pooled, N);
        edge_kernel_atomic<<<nbE, blk, 0, stream>>>(ef, hm, src, dst, Wm2 + DD * DD, pooled, E);
        update_kernel<<<nbN, blk, 0, stream>>>(h1, pooled, Wu2, bu2, h2, N);

        out_kernel<<<nbN, blk, 0, stream>>>(h2, Wo, bo, out, N);
    }
}

// Round 19
// 295.845 us; speedup vs baseline: 1.0605x; 1.0605x over previous
//
#include <hip/hip_runtime.h>

#define DD 64
#define WIN 128    // CSR slots per block
#define MSTR 132   // ldsMT row stride (bf16): 264B rows, 8B-aligned

typedef __attribute__((ext_vector_type(8))) short bf16x8;
typedef __attribute__((ext_vector_type(4))) float f32x4;

__device__ __forceinline__ float fast_tanh(float x) {
    float e = __builtin_amdgcn_exp2f(x * 2.885390081777927f); // 2x * log2(e)
    return 1.0f - 2.0f * __builtin_amdgcn_rcpf(e + 1.0f);
}

__device__ __forceinline__ unsigned f2bf(float f) {
    union { float f; unsigned u; } v; v.f = f;
    return (v.u + 0x7FFFu + ((v.u >> 16) & 1u)) >> 16;   // RNE
}

__device__ __forceinline__ float bf2f(unsigned short u) {
    union { unsigned u; float f; } v; v.u = ((unsigned)u) << 16;
    return v.f;
}

__device__ __forceinline__ bf16x8 cvt8(float4 f0, float4 f1) {
    union { unsigned u[4]; bf16x8 v; } r;
    r.u[0] = f2bf(f0.x) | (f2bf(f0.y) << 16);
    r.u[1] = f2bf(f0.z) | (f2bf(f0.w) << 16);
    r.u[2] = f2bf(f1.x) | (f2bf(f1.y) << 16);
    r.u[3] = f2bf(f1.z) | (f2bf(f1.w) << 16);
    return r.v;
}

// ---------------- CSR build ----------------

__global__ void __launch_bounds__(256) zero_deg(int* __restrict__ deg, int N)
{
    int i = blockIdx.x * 256 + threadIdx.x;
    if (i < N) deg[i] = 0;
}

__global__ void __launch_bounds__(256) count_deg(
    const int* __restrict__ dst, int* __restrict__ deg, int E)
{
    int e = blockIdx.x * 256 + threadIdx.x;
    if (e < E) atomicAdd(&deg[dst[e]], 1);
}

// parallel scan, 3 kernels: per-256-chunk partials -> base scan -> expand
__global__ void __launch_bounds__(256) scan_partial(
    const int* __restrict__ deg, int* __restrict__ part, int N)
{
    __shared__ int red[256];
    int b = blockIdx.x, t = threadIdx.x;
    int i = b * 256 + t;
    red[t] = (i < N) ? deg[i] : 0;
    __syncthreads();
    #pragma unroll
    for (int d = 128; d > 0; d >>= 1) {
        if (t < d) red[t] += red[t + d];
        __syncthreads();
    }
    if (t == 0) part[b] = red[0];
}

__global__ void __launch_bounds__(1024) scan_base(int* __restrict__ part, int nb)
{
    __shared__ int sc[1024];
    int t = threadIdx.x;
    sc[t] = (t < nb) ? part[t] : 0;
    __syncthreads();
    for (int d = 1; d < 1024; d <<= 1) {
        int v = 0;
        if (t >= d) v = sc[t - d];
        __syncthreads();
        if (t >= d) sc[t] += v;
        __syncthreads();
    }
    if (t < nb) part[t] = (t == 0) ? 0 : sc[t - 1];
}

__global__ void __launch_bounds__(256) scan_expand(
    const int* __restrict__ deg, const int* __restrict__ part,
    int* __restrict__ off, int* __restrict__ cursor, int N)
{
    __shared__ int sc[256];
    int b = blockIdx.x, t = threadIdx.x;
    int i = b * 256 + t;
    int d = (i < N) ? deg[i] : 0;
    sc[t] = d;
    __syncthreads();
    for (int s = 1; s < 256; s <<= 1) {
        int v = 0;
        if (t >= s) v = sc[t - s];
        __syncthreads();
        if (t >= s) sc[t] += v;
        __syncthreads();
    }
    int excl = sc[t] - d;
    if (i < N) {
        int o = part[b] + excl;
        off[i] = o; cursor[i] = o;
        if (i == N - 1) off[N] = o + d;
    }
}

// fallback single-block scan (used only if N/256 > 1024)
__global__ void __launch_bounds__(1024) scan_kernel(
    const int* __restrict__ deg, int* __restrict__ off,
    int* __restrict__ cursor, int N)
{
    __shared__ int part[1024];
    int t = threadIdx.x;
    int per = (N + 1023) / 1024;
    int lo = t * per;
    int hi = lo + per; if (hi > N) hi = N;
    int s = 0;
    for (int i = lo; i < hi; ++i) s += deg[i];
    part[t] = s;
    __syncthreads();
    for (int d = 1; d < 1024; d <<= 1) {
        int v = 0;
        if (t >= d) v = part[t - d];
        __syncthreads();
        if (t >= d) part[t] += v;
        __syncthreads();
    }
    int run = (t == 0) ? 0 : part[t - 1];
    for (int i = lo; i < hi; ++i) {
        off[i] = run; cursor[i] = run;
        run += deg[i];
    }
    if (lo < N && hi == N) off[N] = run;
}

// also writes srcc[slot] = src[e] (src[e] coalesced here since e = tid)
__global__ void __launch_bounds__(256) fill_eidx(
    const int* __restrict__ dst, const int* __restrict__ src,
    int* __restrict__ cursor, int* __restrict__ eidx,
    int* __restrict__ srcc, int E)
{
    int e = blockIdx.x * 256 + threadIdx.x;
    if (e < E) {
        int slot = atomicAdd(&cursor[dst[e]], 1);
        eidx[slot] = e;
        srcc[slot] = src[e];
    }
}

// wt[m][n*64+k] = bf16(W_m[(koff+k)*64 + n]) for the 8 half-matrices:
// 0:Wm1 top  1:Wm1 bot  2:Wu1 top  3:Wu1 bot  4:Wm2 top  5:Wm2 bot  6:Wu2 top  7:Wu2 bot
__global__ void __launch_bounds__(256) prep_wt_all(
    const float* __restrict__ Wm1, const float* __restrict__ Wu1,
    const float* __restrict__ Wm2, const float* __restrict__ Wu2,
    unsigned short* __restrict__ wt)
{
    int i = blockIdx.x * 256 + threadIdx.x;
    if (i >= 8 * 4096) return;
    int m = i >> 12;
    int j = i & 4095;
    int n = j >> 6, k = j & 63;
    const float* W; int koff;
    switch (m) {
        case 0: W = Wm1; koff = 0;  break;
        case 1: W = Wm1; koff = 64; break;
        case 2: W = Wu1; koff = 0;  break;
        case 3: W = Wu1; koff = 64; break;
        case 4: W = Wm2; koff = 0;  break;
        case 5: W = Wm2; koff = 64; break;
        case 6: W = Wu2; koff = 0;  break;
        default: W = Wu2; koff = 64; break;
    }
    wt[i] = (unsigned short)f2bf(W[(koff + k) * 64 + n]);
}

// ---------------- MFMA node GEMM ----------------
// out[r] = op(A1[r]@W1 (+ A2[r]@W2) + bias)
// OUTK: fuse final readout, out1[r] = tanh(row)·Wo + bo via shfl reduce.
// NEXT: after computing h = tanh(...), also compute hm = h@Wn + biasn
//       (h goes C-layout -> swizzled LDS -> A-fragments) and zero pooled.
// HM16: main epilogue output is bf16 (the hm table read by the fused
//       kernel's random gather: 12.8->6.4MB halves random-line traffic).
template<bool TWO, bool TANH, bool ZEROP, bool OUTK, bool NEXT, bool HM16>
__global__ void __launch_bounds__(256, 4) node_mfma(
    const float* __restrict__ A1, const float* __restrict__ A2,
    const unsigned short* __restrict__ wt1, const unsigned short* __restrict__ wt2,
    const float* __restrict__ bias, float* __restrict__ outp,
    unsigned short* __restrict__ outp16, float* __restrict__ pooled,
    const float* __restrict__ Wo, const float* __restrict__ bo,
    float* __restrict__ outv,
    const unsigned short* __restrict__ wtn, const float* __restrict__ biasn,
    unsigned short* __restrict__ hmout, int N)
{
    __shared__ unsigned short ldsH[NEXT ? 128 * 64 : 8];

    const int t = threadIdx.x;
    const int row0 = blockIdx.x * 128;
    const int wv = t >> 6, l = t & 63;
    const int lrow = l & 15, lk = l >> 4;

    f32x4 acc[2][4];
    {
        bf16x8 bfr[4][2];
        #pragma unroll
        for (int cg = 0; cg < 4; ++cg)
            #pragma unroll
            for (int k2 = 0; k2 < 2; ++k2)
                bfr[cg][k2] = *reinterpret_cast<const bf16x8*>(
                    wt1 + (cg * 16 + lrow) * 64 + (lk + k2 * 4) * 8);
        #pragma unroll
        for (int er = 0; er < 2; ++er) {
            int r = row0 + wv * 32 + er * 16 + lrow;
            bf16x8 a0, a1;
            if (r < N) {
                const float4* ap = reinterpret_cast<const float4*>(A1 + (size_t)r * 64);
                a0 = cvt8(ap[lk * 2],       ap[lk * 2 + 1]);
                a1 = cvt8(ap[(lk + 4) * 2], ap[(lk + 4) * 2 + 1]);
            } else {
                a0 = bf16x8{0,0,0,0,0,0,0,0}; a1 = a0;
            }
            #pragma unroll
            for (int cg = 0; cg < 4; ++cg) {
                f32x4 zz = {0.f, 0.f, 0.f, 0.f};
                acc[er][cg] = __builtin_amdgcn_mfma_f32_16x16x32_bf16(a0, bfr[cg][0], zz, 0, 0, 0);
                acc[er][cg] = __builtin_amdgcn_mfma_f32_16x16x32_bf16(a1, bfr[cg][1], acc[er][cg], 0, 0, 0);
            }
        }
    }
    if (TWO) {
        bf16x8 bfr[4][2];
        #pragma unroll
        for (int cg = 0; cg < 4; ++cg)
            #pragma unroll
            for (int k2 = 0; k2 < 2; ++k2)
                bfr[cg][k2] = *reinterpret_cast<const bf16x8*>(
                    wt2 + (cg * 16 + lrow) * 64 + (lk + k2 * 4) * 8);
        #pragma unroll
        for (int er = 0; er < 2; ++er) {
            int r = row0 + wv * 32 + er * 16 + lrow;
            bf16x8 a0, a1;
            if (r < N) {
                const float4* ap = reinterpret_cast<const float4*>(A2 + (size_t)r * 64);
                a0 = cvt8(ap[lk * 2],       ap[lk * 2 + 1]);
                a1 = cvt8(ap[(lk + 4) * 2], ap[(lk + 4) * 2 + 1]);
            } else {
                a0 = bf16x8{0,0,0,0,0,0,0,0}; a1 = a0;
            }
            #pragma unroll
            for (int cg = 0; cg < 4; ++cg) {
                acc[er][cg] = __builtin_amdgcn_mfma_f32_16x16x32_bf16(a0, bfr[cg][0], acc[er][cg], 0, 0, 0);
                acc[er][cg] = __builtin_amdgcn_mfma_f32_16x16x32_bf16(a1, bfr[cg][1], acc[er][cg], 0, 0, 0);
            }
        }
    }

    if (!OUTK) {
        // epilogue: C/D mapping col=lane&15, row=(lane>>4)*4+reg (verified)
        #pragma unroll
        for (int er = 0; er < 2; ++er) {
            int rbl = wv * 32 + er * 16 + (lk << 2);   // local row base
            #pragma unroll
            for (int cg = 0; cg < 4; ++cg) {
                int col = cg * 16 + lrow;
                float bv = bias[col];
                #pragma unroll
                for (int j = 0; j < 4; ++j) {
                    int r = row0 + rbl + j;
                    float v = acc[er][cg][j] + bv;
                    if (TANH) v = fast_tanh(v);
                    if (r < N) {
                        if (HM16) outp16[(size_t)r * 64 + col] = (unsigned short)f2bf(v);
                        else      outp[(size_t)r * 64 + col] = v;
                        if (ZEROP) pooled[(size_t)r * 64 + col] = 0.f;
                    }
                    if (NEXT) {
                        int lr = rbl + j;
                        ldsH[(lr * 8 + ((col >> 3) ^ (lr & 7))) * 8 + (col & 7)] =
                            (unsigned short)f2bf(v);
                    }
                }
            }
        }
    } else {
        // fused readout: out[r] = tanh(row+bias)·Wo + bo
        float p0[2], p1[2], p2[2], p3[2];
        #pragma unroll
        for (int er = 0; er < 2; ++er) { p0[er]=0.f; p1[er]=0.f; p2[er]=0.f; p3[er]=0.f; }
        #pragma unroll
        for (int er = 0; er < 2; ++er) {
            #pragma unroll
            for (int cg = 0; cg < 4; ++cg) {
                int col = cg * 16 + lrow;
                float bv = bias[col];
                float wo = Wo[col];
                p0[er] += fast_tanh(acc[er][cg][0] + bv) * wo;
                p1[er] += fast_tanh(acc[er][cg][1] + bv) * wo;
                p2[er] += fast_tanh(acc[er][cg][2] + bv) * wo;
                p3[er] += fast_tanh(acc[er][cg][3] + bv) * wo;
            }
        }
        #pragma unroll
        for (int m = 1; m < 16; m <<= 1) {
            #pragma unroll
            for (int er = 0; er < 2; ++er) {
                p0[er] += __shfl_xor(p0[er], m, 64);
                p1[er] += __shfl_xor(p1[er], m, 64);
                p2[er] += __shfl_xor(p2[er], m, 64);
                p3[er] += __shfl_xor(p3[er], m, 64);
            }
        }
        if (lrow < 4) {
            float bov = bo[0];
            #pragma unroll
            for (int er = 0; er < 2; ++er) {
                int r = row0 + wv * 32 + er * 16 + (lk << 2) + lrow;
                float pv = (lrow == 0) ? p0[er] : (lrow == 1) ? p1[er]
                         : (lrow == 2) ? p2[er] : p3[er];
                if (r < N) outv[r] = pv + bov;
            }
        }
    }

    if (NEXT) {
        __syncthreads();
        // second GEMM: hm = h @ Wn + biasn (h from swizzled LDS) -> bf16
        bf16x8 bfrn[4][2];
        #pragma unroll
        for (int cg = 0; cg < 4; ++cg)
            #pragma unroll
            for (int k2 = 0; k2 < 2; ++k2)
                bfrn[cg][k2] = *reinterpret_cast<const bf16x8*>(
                    wtn + (cg * 16 + lrow) * 64 + (lk + k2 * 4) * 8);
        f32x4 accn[2][4];
        #pragma unroll
        for (int er = 0; er < 2; ++er) {
            int row = wv * 32 + er * 16 + lrow;
            bf16x8 a0 = *reinterpret_cast<const bf16x8*>(
                &ldsH[(row * 8 + ((lk + 0) ^ (row & 7))) * 8]);
            bf16x8 a1 = *reinterpret_cast<const bf16x8*>(
                &ldsH[(row * 8 + ((lk + 4) ^ (row & 7))) * 8]);
            #pragma unroll
            for (int cg = 0; cg < 4; ++cg) {
                f32x4 zz = {0.f, 0.f, 0.f, 0.f};
                accn[er][cg] = __builtin_amdgcn_mfma_f32_16x16x32_bf16(a0, bfrn[cg][0], zz, 0, 0, 0);
                accn[er][cg] = __builtin_amdgcn_mfma_f32_16x16x32_bf16(a1, bfrn[cg][1], accn[er][cg], 0, 0, 0);
            }
        }
        #pragma unroll
        for (int er = 0; er < 2; ++er) {
            int rbl = wv * 32 + er * 16 + (lk << 2);
            #pragma unroll
            for (int cg = 0; cg < 4; ++cg) {
                int col = cg * 16 + lrow;
                float bv = biasn[col];
                #pragma unroll
                for (int j = 0; j < 4; ++j) {
                    int r = row0 + rbl + j;
                    if (r < N) {
                        hmout[(size_t)r * 64 + col] = (unsigned short)f2bf(accn[er][cg][j] + bv);
                        pooled[(size_t)r * 64 + col] = 0.f;
                    }
                }
            }
        }
    }
}

// ---------------- MFMA fused edge kernel v10 ----------------
// round-15 (299us) v8 dataflow with plain (cached) loads; hm is now a BF16
// table (6.4MB): the epilogue's random src-row gathers pull 2x64B lines per
// row instead of 4, halving the L2/L3 random-line service that bounds this
// kernel (round-15 PMC: layer-1 and layer-2 equal at 118us despite 3x
// different streaming traffic -> gather-bound).
__global__ void __launch_bounds__(256, 4) fused_edge_gather(
    const float* __restrict__ ef, unsigned short* __restrict__ efb,
    const unsigned short* __restrict__ hm,
    const int* __restrict__ srcc, const int* __restrict__ dst,
    const int* __restrict__ off, const int* __restrict__ eidx,
    const unsigned short* __restrict__ wtb, float* __restrict__ pooled,
    int E, int N, int layer1)
{
    __shared__ unsigned short ldsMT[64 * MSTR];   // [channel][slot] (16.9 KB)
    __shared__ int ldsE[WIN];
    __shared__ int ldsSrc[WIN];

    const int t  = threadIdx.x;
    const int s0 = blockIdx.x * WIN;
    const int wv = t >> 6, l = t & 63;
    const int lrow = l & 15, lk = l >> 4;

    // stage edge ids + src rows for the window (both coalesced)
    if (t < WIN) {
        int slot = s0 + t;
        ldsE[t]   = (slot < E) ? eidx[slot] : 0;
        ldsSrc[t] = (slot < E) ? srcc[slot] : 0;
    }

    // B fragments from global (8 KB, L2-hot broadcast)
    bf16x8 bfr[4][2];
    #pragma unroll
    for (int cg = 0; cg < 4; ++cg)
        #pragma unroll
        for (int k2 = 0; k2 < 2; ++k2)
            bfr[cg][k2] = *reinterpret_cast<const bf16x8*>(
                wtb + (cg * 16 + lrow) * 64 + (lk + k2 * 4) * 8);

    __syncthreads();

    {
        // A fragments direct from global (+ efb persist on layer 1)
        bf16x8 afr[2][2];
        #pragma unroll
        for (int er = 0; er < 2; ++er) {
            int row = wv * 32 + er * 16 + lrow;
            int slotr = s0 + row;
            if (slotr < E) {
                if (layer1) {
                    int e = ldsE[row];
                    const float4* ap = reinterpret_cast<const float4*>(ef + (size_t)e * 64);
                    #pragma unroll
                    for (int k2 = 0; k2 < 2; ++k2) {
                        int cc = lk + k2 * 4;
                        bf16x8 v = cvt8(ap[cc * 2], ap[cc * 2 + 1]);
                        afr[er][k2] = v;
                        *reinterpret_cast<bf16x8*>(efb + (size_t)slotr * 64 + cc * 8) = v;
                    }
                } else {
                    #pragma unroll
                    for (int k2 = 0; k2 < 2; ++k2) {
                        int cc = lk + k2 * 4;
                        afr[er][k2] = *reinterpret_cast<const bf16x8*>(
                            efb + (size_t)slotr * 64 + cc * 8);
                    }
                }
            } else {
                bf16x8 z = {0,0,0,0,0,0,0,0};
                afr[er][0] = z; afr[er][1] = z;
            }
        }

        // MFMA [128x64] = A @ Wt; epilogue: + bf16 hm[src] (16-lane x 32B
        // contiguous gathers, 2 lines/row), tanh, bf16 -> ldsMT
        #pragma unroll
        for (int er = 0; er < 2; ++er) {
            f32x4 acc[4];
            #pragma unroll
            for (int cg = 0; cg < 4; ++cg) {
                f32x4 zz = {0.f, 0.f, 0.f, 0.f};
                acc[cg] = __builtin_amdgcn_mfma_f32_16x16x32_bf16(
                    afr[er][0], bfr[cg][0], zz, 0, 0, 0);
                acc[cg] = __builtin_amdgcn_mfma_f32_16x16x32_bf16(
                    afr[er][1], bfr[cg][1], acc[cg], 0, 0, 0);
            }
            int rb = wv * 32 + er * 16 + (lk << 2);
            int sA = ldsSrc[rb + 0], sB = ldsSrc[rb + 1];
            int sC = ldsSrc[rb + 2], sD = ldsSrc[rb + 3];
            #pragma unroll
            for (int cg = 0; cg < 4; ++cg) {
                int col = cg * 16 + lrow;
                float hA = bf2f(hm[(size_t)sA * 64 + col]);
                float hB = bf2f(hm[(size_t)sB * 64 + col]);
                float hC = bf2f(hm[(size_t)sC * 64 + col]);
                float hD = bf2f(hm[(size_t)sD * 64 + col]);
                unsigned short* mcol = &ldsMT[col * MSTR];
                ushort4 m4;
                m4.x = (unsigned short)f2bf(fast_tanh(acc[cg][0] + hA));
                m4.y = (unsigned short)f2bf(fast_tanh(acc[cg][1] + hB));
                m4.z = (unsigned short)f2bf(fast_tanh(acc[cg][2] + hC));
                m4.w = (unsigned short)f2bf(fast_tanh(acc[cg][3] + hD));
                *reinterpret_cast<ushort4*>(&mcol[rb]) = m4;
            }
        }
    }
    __syncthreads();

    // phase 2: segment-sum over the window; wave per node, lane = channel;
    // lane l reads consecutive slots of its channel row -> ushort4 loads.
    {
        int ce = s0 + WIN; if (ce > E) ce = E;
        if (s0 < E) {
            int df = dst[ldsE[0]];
            int dl = dst[ldsE[ce - 1 - s0]];
            const unsigned short* mrow = &ldsMT[l * MSTR];
            for (int n = df + wv; n <= dl; n += 4) {
                int lo = off[n], hi = off[n + 1];
                int clo = lo > s0 ? lo : s0;
                int chi = hi < ce ? hi : ce;
                if (clo >= chi) continue;
                float v = 0.f;
                int q = clo - s0, qe = chi - s0;
                for (; (q & 3) && q < qe; ++q) v += bf2f(mrow[q]);
                for (; q + 3 < qe; q += 4) {
                    ushort4 m4 = *reinterpret_cast<const ushort4*>(mrow + q);
                    v += (bf2f(m4.x) + bf2f(m4.y)) + (bf2f(m4.z) + bf2f(m4.w));
                }
                for (; q < qe; ++q) v += bf2f(mrow[q]);
                if (lo >= s0 && hi <= ce) pooled[(size_t)n * 64 + l] = v;
                else atomicAdd(pooled + (size_t)n * 64 + l, v);
            }
        }
    }
}

// ---------------- scalar fallback kernels (ws too small; fp32 exact) ----------------

__global__ void __launch_bounds__(256, 2) node_transform(
    const float* __restrict__ h, const float* __restrict__ W,
    const float* __restrict__ b, float* __restrict__ hm,
    float* __restrict__ pooled, int N)
{
    int n = blockIdx.x * 256 + threadIdx.x;
    if (n >= N) return;
    float acc[DD];
    #pragma unroll
    for (int j = 0; j < DD; ++j) acc[j] = b[j];
    const float4* hrow = reinterpret_cast<const float4*>(h + (size_t)n * DD);
    #pragma unroll
    for (int kk = 0; kk < DD / 4; ++kk) {
        float4 a = hrow[kk];
        const float* Wr = W + kk * 4 * DD;
        #pragma unroll
        for (int j = 0; j < DD; ++j)
            acc[j] += a.x * Wr[j] + a.y * Wr[DD + j]
                    + a.z * Wr[2 * DD + j] + a.w * Wr[3 * DD + j];
    }
    float4* orow = reinterpret_cast<float4*>(hm + (size_t)n * DD);
    float4* prow = reinterpret_cast<float4*>(pooled + (size_t)n * DD);
    #pragma unroll
    for (int jj = 0; jj < DD / 4; ++jj) {
        orow[jj] = make_float4(acc[4*jj], acc[4*jj+1], acc[4*jj+2], acc[4*jj+3]);
        prow[jj] = make_float4(0.f, 0.f, 0.f, 0.f);
    }
}

__global__ void __launch_bounds__(256, 2) edge_kernel_atomic(
    const float* __restrict__ ef, const float* __restrict__ hm,
    const int* __restrict__ src, const int* __restrict__ dst,
    const float* __restrict__ W, float* __restrict__ pooled, int E)
{
    int e = blockIdx.x * 256 + threadIdx.x;
    if (e >= E) return;
    int s = src[e];
    int d = dst[e];
    float acc[DD];
    #pragma unroll
    for (int j = 0; j < DD; ++j) acc[j] = 0.0f;
    const float4* erow = reinterpret_cast<const float4*>(ef + (size_t)e * DD);
    #pragma unroll
    for (int kk = 0; kk < DD / 4; ++kk) {
        float4 a = erow[kk];
        const float* Wr = W + kk * 4 * DD;
        #pragma unroll
        for (int j = 0; j < DD; ++j)
            acc[j] += a.x * Wr[j] + a.y * Wr[DD + j]
                    + a.z * Wr[2 * DD + j] + a.w * Wr[3 * DD + j];
    }
    const float4* hrow = reinterpret_cast<const float4*>(hm + (size_t)s * DD);
    float* prow = pooled + (size_t)d * DD;
    #pragma unroll
    for (int jj = 0; jj < DD / 4; ++jj) {
        float4 hv = hrow[jj];
        atomicAdd(prow + 4*jj + 0, fast_tanh(acc[4*jj+0] + hv.x));
        atomicAdd(prow + 4*jj + 1, fast_tanh(acc[4*jj+1] + hv.y));
        atomicAdd(prow + 4*jj + 2, fast_tanh(acc[4*jj+2] + hv.z));
        atomicAdd(prow + 4*jj + 3, fast_tanh(acc[4*jj+3] + hv.w));
    }
}

__global__ void __launch_bounds__(256, 2) update_kernel(
    const float* __restrict__ h, const float* __restrict__ pooled,
    const float* __restrict__ Wu, const float* __restrict__ bu,
    float* __restrict__ hout, int N)
{
    int n = blockIdx.x * 256 + threadIdx.x;
    if (n >= N) return;
    float acc[DD];
    #pragma unroll
    for (int j = 0; j < DD; ++j) acc[j] = bu[j];
    const float4* hrow = reinterpret_cast<const float4*>(h + (size_t)n * DD);
    #pragma unroll
    for (int kk = 0; kk < DD / 4; ++kk) {
        float4 a = hrow[kk];
        const float* Wr = Wu + kk * 4 * DD;
        #pragma unroll
        for (int j = 0; j < DD; ++j)
            acc[j] += a.x * Wr[j] + a.y * Wr[DD + j]
                    + a.z * Wr[2 * DD + j] + a.w * Wr[3 * DD + j];
    }
    const float4* prow = reinterpret_cast<const float4*>(pooled + (size_t)n * DD);
    #pragma unroll
    for (int kk = 0; kk < DD / 4; ++kk) {
        float4 a = prow[kk];
        const float* Wr = Wu + (DD + kk * 4) * DD;
        #pragma unroll
        for (int j = 0; j < DD; ++j)
            acc[j] += a.x * Wr[j] + a.y * Wr[DD + j]
                    + a.z * Wr[2 * DD + j] + a.w * Wr[3 * DD + j];
    }
    float4* orow = reinterpret_cast<float4*>(hout + (size_t)n * DD);
    #pragma unroll
    for (int jj = 0; jj < DD / 4; ++jj)
        orow[jj] = make_float4(fast_tanh(acc[4*jj]),   fast_tanh(acc[4*jj+1]),
                               fast_tanh(acc[4*jj+2]), fast_tanh(acc[4*jj+3]));
}

__global__ void __launch_bounds__(256) out_kernel(
    const float* __restrict__ h, const float* __restrict__ Wo,
    const float* __restrict__ bo, float* __restrict__ out, int N)
{
    int n = blockIdx.x * 256 + threadIdx.x;
    if (n >= N) return;
    const float4* hrow = reinterpret_cast<const float4*>(h + (size_t)n * DD);
    float acc = bo[0];
    #pragma unroll
    for (int kk = 0; kk < DD / 4; ++kk) {
        float4 a = hrow[kk];
        acc += a.x * Wo[4*kk] + a.y * Wo[4*kk+1] + a.z * Wo[4*kk+2] + a.w * Wo[4*kk+3];
    }
    out[n] = acc;
}

extern "C" void kernel_launch(void* const* d_in, const int* in_sizes, int n_in,
                              void* d_out, int out_size, void* d_ws, size_t ws_size,
                              hipStream_t stream) {
    const float* node = (const float*)d_in[0];
    const float* ef   = (const float*)d_in[1];
    const int*   src  = (const int*)d_in[2];
    const int*   dst  = (const int*)d_in[3];
    const float* Wm1  = (const float*)d_in[4];
    const float* bm1  = (const float*)d_in[5];
    const float* Wu1  = (const float*)d_in[6];
    const float* bu1  = (const float*)d_in[7];
    const float* Wm2  = (const float*)d_in[8];
    const float* bm2  = (const float*)d_in[9];
    const float* Wu2  = (const float*)d_in[10];
    const float* bu2  = (const float*)d_in[11];
    const float* Wo   = (const float*)d_in[12];
    const float* bo   = (const float*)d_in[13];
    float* out = (float*)d_out;

    const int N = in_sizes[0] / DD;
    const int E = in_sizes[2];

    // ws layout (hm region keeps fp32 size; bf16 path uses first half,
    // fp32 fallback path uses it as float*)
    char* p = (char*)d_ws;
    float* h1     = (float*)p; p += (size_t)N * DD * 4;
    float* h2     = (float*)p; p += (size_t)N * DD * 4;   // fallback only
    char*  hmRaw  = p;         p += (size_t)N * DD * 4;
    float* pooled = (float*)p; p += (size_t)N * DD * 4;
    unsigned short* efb = (unsigned short*)p; p += (size_t)E * DD * 2;
    unsigned short* wt  = (unsigned short*)p; p += (size_t)8 * DD * DD * 2;
    int*   deg    = (int*)p;   p += (size_t)N * 4;
    int*   off    = (int*)p;   p += (size_t)(N + 1) * 4;
    int*   cursor = (int*)p;   p += (size_t)N * 4;
    int*   eidx   = (int*)p;   p += (size_t)E * 4;
    int*   srcc   = (int*)p;   p += (size_t)E * 4;
    int*   part   = (int*)p;   p += (size_t)1024 * 4;
    size_t needed = (size_t)(p - (char*)d_ws);

    unsigned short* hm16 = (unsigned short*)hmRaw;
    float*          hmF  = (float*)hmRaw;

    dim3 blk(256);
    int nbN = (N + 255) / 256;
    int nbE = (E + 255) / 256;
    int nbE2 = (E + WIN - 1) / WIN;
    int nbT = (N + 127) / 128;
    int nbS = (N + 255) / 256;   // scan chunks of 256

    if (ws_size >= needed) {
        // ---- CSR build + weight prep (stateless: rebuilt every call) ----
        zero_deg<<<nbS, blk, 0, stream>>>(deg, N);
        count_deg<<<nbE, blk, 0, stream>>>(dst, deg, E);
        if (nbS <= 1024) {
            scan_partial<<<nbS, blk, 0, stream>>>(deg, part, N);
            scan_base<<<1, 1024, 0, stream>>>(part, nbS);
            scan_expand<<<nbS, blk, 0, stream>>>(deg, part, off, cursor, N);
        } else {
            scan_kernel<<<1, 1024, 0, stream>>>(deg, off, cursor, N);
        }
        fill_eidx<<<nbE, blk, 0, stream>>>(dst, src, cursor, eidx, srcc, E);
        prep_wt_all<<<128, blk, 0, stream>>>(Wm1, Wu1, Wm2, Wu2, wt);

        // ---- layer 1 ----
        node_mfma<false, false, true, false, false, true><<<nbT, blk, 0, stream>>>(
            node, nullptr, wt + 0 * 4096, nullptr, bm1, nullptr, hm16, pooled,
            nullptr, nullptr, nullptr, nullptr, nullptr, nullptr, N);
        fused_edge_gather<<<nbE2, blk, 0, stream>>>(ef, efb, hm16, srcc, dst, off, eidx,
                                                    wt + 1 * 4096, pooled, E, N, 1);
        // update1 fused with node_transform2: h1 fp32 + hm2 bf16, zero pooled
        node_mfma<true, true, false, false, true, false><<<nbT, blk, 0, stream>>>(
            node, pooled, wt + 2 * 4096, wt + 3 * 4096, bu1, h1, nullptr, pooled,
            nullptr, nullptr, nullptr, wt + 4 * 4096, bm2, hm16, N);

        // ---- layer 2 ----
        fused_edge_gather<<<nbE2, blk, 0, stream>>>(ef, efb, hm16, srcc, dst, off, eidx,
                                                    wt + 5 * 4096, pooled, E, N, 0);
        // update2 fused with readout: h2 never materialized
        node_mfma<true, true, false, true, false, false><<<nbT, blk, 0, stream>>>(
            h1, pooled, wt + 6 * 4096, wt + 7 * 4096, bu2, nullptr, nullptr, nullptr,
            Wo, bo, out, nullptr, nullptr, nullptr, N);
    } else {
        // ---- fallback: atomic scatter path (fp32 exact) ----
        node_transform<<<nbN, blk, 0, stream>>>(node, Wm1, bm1, hmF, pooled, N);
        edge_kernel_atomic<<<nbE, blk, 0, stream>>>(ef, hmF, src, dst, Wm1 + DD * DD, pooled, E);
        update_kernel<<<nbN, blk, 0, stream>>>(node, pooled, Wu1, bu1, h1, N);

        node_transform<<<nbN, blk, 0, stream>>>(h1, Wm2, bm2, hmF, pooled, N);
        edge_kernel_atomic<<<nbE, blk, 0, stream>>>(ef, hmF, src, dst, Wm2 + DD * DD, pooled, E);
        update_kernel<<<nbN, blk, 0, stream>>>(h1, pooled, Wu2, bu2, h2, N);

        out_kernel<<<nbN, blk, 0, stream>>>(h2, Wo, bo, out, N);
    }
}